// Round 2
// baseline (6727.699 us; speedup 1.0000x reference)
//
#include <hip/hip_runtime.h>

// ---------------------------------------------------------------------------
// ClassificationNCA — Round 1: one thread = one cell; weights are wave-uniform
// -> scalar (SGPR) loads; hot loop is a pure v_fmac_f32(vacc, s_w, v_p) stream.
// p[87] + h2[128] accumulators live in VGPRs; no activation LDS; one barrier.
// ---------------------------------------------------------------------------

#define ROTL32(x, d) (((x) << (d)) | ((x) >> (32 - (d))))

struct U2 { unsigned a, b; };

__host__ __device__ inline U2 tf2x32(unsigned k0, unsigned k1, unsigned c0, unsigned c1) {
  unsigned ks2 = k0 ^ k1 ^ 0x1BD11BDAu;
  unsigned x0 = c0 + k0;
  unsigned x1 = c1 + k1;
#define TF_ROUND4(r0, r1, r2, r3)                                              \
  x0 += x1; x1 = ROTL32(x1, r0); x1 ^= x0;                                     \
  x0 += x1; x1 = ROTL32(x1, r1); x1 ^= x0;                                     \
  x0 += x1; x1 = ROTL32(x1, r2); x1 ^= x0;                                     \
  x0 += x1; x1 = ROTL32(x1, r3); x1 ^= x0;
  TF_ROUND4(13, 15, 26, 6)
  x0 += k1;  x1 += ks2 + 1u;
  TF_ROUND4(17, 29, 16, 24)
  x0 += ks2; x1 += k0 + 2u;
  TF_ROUND4(13, 15, 26, 6)
  x0 += k0;  x1 += k1 + 3u;
  TF_ROUND4(17, 29, 16, 24)
  x0 += k1;  x1 += ks2 + 4u;
  TF_ROUND4(13, 15, 26, 6)
  x0 += ks2; x1 += k0 + 5u;
#undef TF_ROUND4
  U2 r; r.a = x0; r.b = x1; return r;
}

// XLA ErfInv32 (Giles polynomials) — matches lax.erf_inv on f32.
__device__ inline float erfinv_xla(float x) {
  float w = -log1pf(-x * x);
  float p;
  if (w < 5.0f) {
    w -= 2.5f;
    p = 2.81022636e-08f;
    p = fmaf(p, w, 3.43273939e-07f);
    p = fmaf(p, w, -3.5233877e-06f);
    p = fmaf(p, w, -4.39150654e-06f);
    p = fmaf(p, w, 0.00021858087f);
    p = fmaf(p, w, -0.00125372503f);
    p = fmaf(p, w, -0.00417768164f);
    p = fmaf(p, w, 0.246640727f);
    p = fmaf(p, w, 1.50140941f);
  } else {
    w = sqrtf(w) - 3.0f;
    p = -0.000200214257f;
    p = fmaf(p, w, 0.000100950558f);
    p = fmaf(p, w, 0.00134934322f);
    p = fmaf(p, w, -0.00367342844f);
    p = fmaf(p, w, 0.00573950773f);
    p = fmaf(p, w, -0.0076224613f);
    p = fmaf(p, w, 0.00943887047f);
    p = fmaf(p, w, 1.00167406f);
    p = fmaf(p, w, 2.83297682f);
  }
  return p * x;
}

__device__ inline float leaky(float v) { return v >= 0.0f ? v : 0.01f * v; }

// ---------------------------------------------------------------------------
// Weight prep: w2 (128x256) -> w2t (256x128, o-major rows of 128);
//              w3 (29x128)  -> w3t (128x32, j-major rows, zero-padded).
// w1 (256x88) and b1 are used in their original layout (o-major rows).
// ---------------------------------------------------------------------------
__global__ void prep_weights(const float* __restrict__ w2, const float* __restrict__ w3,
                             float* __restrict__ w2t, float* __restrict__ w3t) {
  int i = blockIdx.x * 256 + threadIdx.x;
  if (i < 256 * 128) { int o = i >> 7, j = i & 127; w2t[i] = w2[j * 256 + o]; }
  if (i < 128 * 32) { int j = i >> 5, c = i & 31; w3t[i] = (c < 29) ? w3[c * 128 + j] : 0.0f; }
}

// ---------------------------------------------------------------------------
// State init. Channels 0..2 (= x) never change (chan_mask) — write them into
// BOTH ping-pong buffers once; nca_step never rewrites them.
// ---------------------------------------------------------------------------
__global__ void init_state(const float* __restrict__ x, float* __restrict__ s0,
                           float* __restrict__ s1, unsigned hk0, unsigned hk1) {
  int idx = blockIdx.x * 256 + threadIdx.x;
  if (idx >= 16 * 29 * 4096) return;
  int pix = idx & 4095;
  int c = (idx >> 12) % 29;
  int b = idx / (4096 * 29);
  float v;
  if (c < 3) {
    v = x[(b * 3 + c) * 4096 + pix];
    s1[idx] = v;
  } else if (c < 19) {
    int ch = c - 3;
    int i = (b * 16 + ch) * 4096 + pix;  // linear index into (16,16,64,64)
    const int half = 131072;
    unsigned bits;
    if (i < half) bits = tf2x32(hk0, hk1, (unsigned)i, (unsigned)(i + half)).a;
    else          bits = tf2x32(hk0, hk1, (unsigned)(i - half), (unsigned)i).b;
    float f = __uint_as_float((bits >> 9) | 0x3F800000u) - 1.0f;
    const float lo = -0x1.fffffep-1f;
    float u = fmaxf(lo, fmaf(f, 2.0f, lo));
    v = fmaf(0.225f, 1.41421356237f * erfinv_xla(u), 0.5f);
  } else {
    v = 0.0f;
  }
  s0[idx] = v;
}

// ---------------------------------------------------------------------------
// One NCA step. Block = 128 threads = one 64x2 cell tile. Per thread:
//   perception (LDS halo stencil) -> ps/px/py regs,
//   fused layer1+layer2 over o=0..255 (scalar weight loads),
//   layer3 fully unrolled (h2 stays in regs), fire mask, residual store.
// ---------------------------------------------------------------------------
__global__ __launch_bounds__(128, 2) void nca_step(
    const float* __restrict__ sin_, float* __restrict__ sout,
    const float* __restrict__ w1, const float* __restrict__ b1,
    const float* __restrict__ w2t, const float* __restrict__ w3t,
    float tval, unsigned fk0, unsigned fk1) {
  __shared__ float sS[29 * 4 * 66];  // rows ty0-1..ty0+2, cols -1..64; 30.6 KB

  const int tid = threadIdx.x;
  const int b = blockIdx.z;
  const int ty0 = blockIdx.y * 2;
  const float* sb = sin_ + b * 29 * 4096;

  // --- halo load (zero padded) ---
  for (int l = tid; l < 29 * 264; l += 128) {
    int c = l / 264;
    int rem = l - c * 264;
    int r = rem / 66;
    int x = rem - r * 66;
    int gy = ty0 - 1 + r, gx = x - 1;
    float v = 0.0f;
    if ((unsigned)gy < 64u && (unsigned)gx < 64u) v = sb[c * 4096 + gy * 64 + gx];
    sS[l] = v;
  }
  __syncthreads();

  const int lx = tid & 63, ly = tid >> 6;
  const int gy = ty0 + ly, gx = lx;

  // --- perception: ps/px/py registers ---
  float ps[29], px[29], py[29];
#pragma unroll
  for (int c = 0; c < 29; ++c) {
    const float* S = sS + c * 264 + (ly + 1) * 66 + (lx + 1);
    float m00 = S[-67], m01 = S[-66], m02 = S[-65];
    float m10 = S[-1],  m11 = S[0],   m12 = S[1];
    float m20 = S[65],  m21 = S[66],  m22 = S[67];
    ps[c] = m11;
    px[c] = ((m02 - m00) + 2.0f * (m12 - m10) + (m22 - m20)) * 0.125f;
    py[c] = ((m20 + 2.0f * m21 + m22) - (m00 + 2.0f * m01 + m02)) * 0.125f;
  }

  // --- fused layer1 + layer2 ---
  float h2a[128];
#pragma unroll
  for (int j = 0; j < 128; ++j) h2a[j] = 0.0f;

#pragma unroll 2
  for (int o = 0; o < 256; ++o) {
    const float* wr = w1 + o * 88;  // uniform address -> scalar loads
    float a0 = 0.0f, a1 = 0.0f, a2 = 0.0f, a3 = 0.0f;
#pragma unroll
    for (int k = 0; k < 88; k += 4) {
      float p0 = (k + 0 < 29) ? ps[k + 0] : (k + 0 < 58) ? px[k - 29] : (k + 0 < 87) ? py[k - 58] : tval;
      float p1 = (k + 1 < 29) ? ps[k + 1] : (k + 1 < 58) ? px[k + 1 - 29] : (k + 1 < 87) ? py[k + 1 - 58] : tval;
      float p2 = (k + 2 < 29) ? ps[k + 2] : (k + 2 < 58) ? px[k + 2 - 29] : (k + 2 < 87) ? py[k + 2 - 58] : tval;
      float p3 = (k + 3 < 29) ? ps[k + 3] : (k + 3 < 58) ? px[k + 3 - 29] : (k + 3 < 87) ? py[k + 3 - 58] : tval;
      a0 = fmaf(p0, wr[k + 0], a0);
      a1 = fmaf(p1, wr[k + 1], a1);
      a2 = fmaf(p2, wr[k + 2], a2);
      a3 = fmaf(p3, wr[k + 3], a3);
    }
    float h1 = leaky(((a0 + a1) + (a2 + a3)) + b1[o]);
    const float* w2r = w2t + o * 128;  // uniform address -> scalar loads
#pragma unroll
    for (int j = 0; j < 128; ++j) h2a[j] = fmaf(h1, w2r[j], h2a[j]);
  }

  // --- layer3 (fully unrolled: h2a must stay in registers) ---
  float dxa[29];
#pragma unroll
  for (int c = 3; c < 29; ++c) dxa[c] = 0.0f;
#pragma unroll
  for (int j = 0; j < 128; ++j) {
    float h = leaky(h2a[j]);
    const float* w3r = w3t + j * 32;  // uniform address -> scalar loads
#pragma unroll
    for (int c = 3; c < 29; ++c) dxa[c] = fmaf(h, w3r[c], dxa[c]);
  }

  // --- fire mask (bit-exact JAX uniform < 0.5) ---
  int i = b * 4096 + gy * 64 + gx;
  unsigned bits;
  if (i < 32768) bits = tf2x32(fk0, fk1, (unsigned)i, (unsigned)(i + 32768)).a;
  else           bits = tf2x32(fk0, fk1, (unsigned)(i - 32768), (unsigned)i).b;
  float fire = (bits & 0x80000000u) ? 0.0f : 1.0f;

  // --- residual store (channels 3..28; 0..2 are static in both buffers) ---
  float* ob = sout + b * 29 * 4096 + gy * 64 + gx;
#pragma unroll
  for (int c = 3; c < 29; ++c) ob[c * 4096] = fmaf(fire, dxa[c], ps[c]);
}

// ---------------------------------------------------------------------------
// Final: logits[b][o] = mean(state[b][19+o]); softmax over o.
// ---------------------------------------------------------------------------
__global__ __launch_bounds__(256) void finalize(const float* __restrict__ s,
                                                float* __restrict__ out) {
  __shared__ float red[256];
  __shared__ float ls[10];
  int b = blockIdx.x, tid = threadIdx.x;
  const float* sb = s + b * 29 * 4096;
  for (int o = 0; o < 10; ++o) {
    const float* ch = sb + (19 + o) * 4096;
    float p = 0.0f;
    for (int i = tid; i < 4096; i += 256) p += ch[i];
    red[tid] = p;
    __syncthreads();
    for (int st = 128; st > 0; st >>= 1) {
      if (tid < st) red[tid] += red[tid + st];
      __syncthreads();
    }
    if (tid == 0) ls[o] = red[0] * (1.0f / 4096.0f);
    __syncthreads();
  }
  if (tid == 0) {
    float m = ls[0];
    for (int o = 1; o < 10; ++o) m = fmaxf(m, ls[o]);
    float e[10], sum = 0.0f;
    for (int o = 0; o < 10; ++o) { e[o] = expf(ls[o] - m); sum += e[o]; }
    for (int o = 0; o < 10; ++o) out[b * 10 + o] = e[o] / sum;
  }
}

// ---------------------------------------------------------------------------
extern "C" void kernel_launch(void* const* d_in, const int* in_sizes, int n_in,
                              void* d_out, int out_size, void* d_ws, size_t ws_size,
                              hipStream_t stream) {
  const float* x  = (const float*)d_in[0];
  const float* w1 = (const float*)d_in[1];
  const float* b1 = (const float*)d_in[2];
  const float* w2 = (const float*)d_in[3];
  const float* w3 = (const float*)d_in[4];
  const int STEPS = 20;  // setup_inputs() fixes steps=20

  const size_t STATE = (size_t)16 * 29 * 4096;
  float* ws = (float*)d_ws;
  float* s0 = ws;
  float* s1 = ws + STATE;
  float* w2t = ws + 2 * STATE;
  float* w3t = w2t + 256 * 128;
  (void)ws_size; (void)n_in; (void)in_sizes; (void)out_size;

  prep_weights<<<128, 256, 0, stream>>>(w2, w3, w2t, w3t);

  U2 hk = tf2x32(0u, 42u, 0u, 10000u);  // fold_in(key(42), 10000)
  init_state<<<(16 * 29 * 4096 + 255) / 256, 256, 0, stream>>>(x, s0, s1, hk.a, hk.b);

  for (int s = 0; s < STEPS; ++s) {
    U2 fk = tf2x32(0u, 42u, 0u, (unsigned)s);  // fold_in(key(42), step)
    float tval = (float)s / 100.0f;
    const float* in = (s & 1) ? s1 : s0;
    float* out = (s & 1) ? s0 : s1;
    dim3 grid(1, 32, 16);  // 64x2 tiles over 64x64, per batch
    nca_step<<<grid, 128, 0, stream>>>(in, out, w1, b1, w2t, w3t, tval, fk.a, fk.b);
  }
  finalize<<<16, 256, 0, stream>>>(s0, (float*)d_out);
}

// Round 3
// 2183.675 us; speedup vs baseline: 3.0809x; 3.0809x over previous
//
#include <hip/hip_runtime.h>

// ---------------------------------------------------------------------------
// ClassificationNCA — Round 2: MFMA (bf16 3-term split) per-step kernel.
// Block = 256 thr = 4 waves; M=64 cells (4x16 tile); wave w owns m-strip w
// for ALL layers -> h1c/h2 LDS rows are wave-private (no barriers in K-loop).
// Layer1->Layer2 fused over 8 n-chunks of 32. LDS = exactly 64 KB, swizzled.
// Weights pre-split to bf16 hi/lo (L2-resident). 3 barriers/step.
// ---------------------------------------------------------------------------

#define ROTL32(x, d) (((x) << (d)) | ((x) >> (32 - (d))))

struct U2 { unsigned a, b; };

__host__ __device__ inline U2 tf2x32(unsigned k0, unsigned k1, unsigned c0, unsigned c1) {
  unsigned ks2 = k0 ^ k1 ^ 0x1BD11BDAu;
  unsigned x0 = c0 + k0;
  unsigned x1 = c1 + k1;
#define TF_ROUND4(r0, r1, r2, r3)                                              \
  x0 += x1; x1 = ROTL32(x1, r0); x1 ^= x0;                                     \
  x0 += x1; x1 = ROTL32(x1, r1); x1 ^= x0;                                     \
  x0 += x1; x1 = ROTL32(x1, r2); x1 ^= x0;                                     \
  x0 += x1; x1 = ROTL32(x1, r3); x1 ^= x0;
  TF_ROUND4(13, 15, 26, 6)
  x0 += k1;  x1 += ks2 + 1u;
  TF_ROUND4(17, 29, 16, 24)
  x0 += ks2; x1 += k0 + 2u;
  TF_ROUND4(13, 15, 26, 6)
  x0 += k0;  x1 += k1 + 3u;
  TF_ROUND4(17, 29, 16, 24)
  x0 += k1;  x1 += ks2 + 4u;
  TF_ROUND4(13, 15, 26, 6)
  x0 += ks2; x1 += k0 + 5u;
#undef TF_ROUND4
  U2 r; r.a = x0; r.b = x1; return r;
}

__device__ inline float erfinv_xla(float x) {
  float w = -log1pf(-x * x);
  float p;
  if (w < 5.0f) {
    w -= 2.5f;
    p = 2.81022636e-08f;
    p = fmaf(p, w, 3.43273939e-07f);
    p = fmaf(p, w, -3.5233877e-06f);
    p = fmaf(p, w, -4.39150654e-06f);
    p = fmaf(p, w, 0.00021858087f);
    p = fmaf(p, w, -0.00125372503f);
    p = fmaf(p, w, -0.00417768164f);
    p = fmaf(p, w, 0.246640727f);
    p = fmaf(p, w, 1.50140941f);
  } else {
    w = sqrtf(w) - 3.0f;
    p = -0.000200214257f;
    p = fmaf(p, w, 0.000100950558f);
    p = fmaf(p, w, 0.00134934322f);
    p = fmaf(p, w, -0.00367342844f);
    p = fmaf(p, w, 0.00573950773f);
    p = fmaf(p, w, -0.0076224613f);
    p = fmaf(p, w, 0.00943887047f);
    p = fmaf(p, w, 1.00167406f);
    p = fmaf(p, w, 2.83297682f);
  }
  return p * x;
}

__device__ inline float leaky(float v) { return v >= 0.0f ? v : 0.01f * v; }

typedef __attribute__((ext_vector_type(8))) short bf16x8;
typedef __attribute__((ext_vector_type(4))) float f32x4;

__device__ inline unsigned short bf16_rne(float x) {
  unsigned u = __float_as_uint(x);
  return (unsigned short)((u + 0x7FFFu + ((u >> 16) & 1u)) >> 16);
}

// split 8 f32 -> bf16 hi + bf16 lo fragments
__device__ inline void split8(const float v[8], bf16x8& hi, bf16x8& lo) {
#pragma unroll
  for (int j = 0; j < 8; ++j) {
    unsigned short h = bf16_rne(v[j]);
    float hf = __uint_as_float(((unsigned)h) << 16);
    unsigned short l = bf16_rne(v[j] - hf);
    hi[j] = (short)h;
    lo[j] = (short)l;
  }
}

// XOR swizzle of 16B groups within 128B octets: byte offset within a row.
__device__ inline int swz(int m, int byteoff) {
  int g = byteoff >> 4;
  g = (g & ~7) | ((g ^ (m & 7)) & 7);
  return (g << 4) | (byteoff & 15);
}

#define MFMA(a, b, c) __builtin_amdgcn_mfma_f32_16x16x32_bf16((a), (b), (c), 0, 0, 0)

// ---------------------------------------------------------------------------
// Weight prep: split to bf16 hi/lo, pad K: w1 [256][96], w2 [128][256]
// (native layout!), w3 [32][128] (rows 29..31 zero).
// ---------------------------------------------------------------------------
__global__ void prep_weights(const float* __restrict__ w1, const float* __restrict__ w2,
                             const float* __restrict__ w3,
                             unsigned short* __restrict__ w1h, unsigned short* __restrict__ w1l,
                             unsigned short* __restrict__ w2h, unsigned short* __restrict__ w2l,
                             unsigned short* __restrict__ w3h, unsigned short* __restrict__ w3l) {
  int i = blockIdx.x * 256 + threadIdx.x;
  if (i < 256 * 96) {
    int n = i / 96, k = i - n * 96;
    float v = (k < 88) ? w1[n * 88 + k] : 0.0f;
    unsigned short h = bf16_rne(v);
    w1h[i] = h;
    w1l[i] = bf16_rne(v - __uint_as_float(((unsigned)h) << 16));
  }
  if (i < 128 * 256) {
    float v = w2[i];
    unsigned short h = bf16_rne(v);
    w2h[i] = h;
    w2l[i] = bf16_rne(v - __uint_as_float(((unsigned)h) << 16));
  }
  if (i < 32 * 128) {
    int n = i >> 7;
    float v = (n < 29) ? w3[i] : 0.0f;
    unsigned short h = bf16_rne(v);
    w3h[i] = h;
    w3l[i] = bf16_rne(v - __uint_as_float(((unsigned)h) << 16));
  }
}

// ---------------------------------------------------------------------------
// State init (channels 0..2 = x static in BOTH buffers).
// ---------------------------------------------------------------------------
__global__ void init_state(const float* __restrict__ x, float* __restrict__ s0,
                           float* __restrict__ s1, unsigned hk0, unsigned hk1) {
  int idx = blockIdx.x * 256 + threadIdx.x;
  if (idx >= 16 * 29 * 4096) return;
  int pix = idx & 4095;
  int c = (idx >> 12) % 29;
  int b = idx / (4096 * 29);
  float v;
  if (c < 3) {
    v = x[(b * 3 + c) * 4096 + pix];
    s1[idx] = v;
  } else if (c < 19) {
    int ch = c - 3;
    int i = (b * 16 + ch) * 4096 + pix;
    const int half = 131072;
    unsigned bits;
    if (i < half) bits = tf2x32(hk0, hk1, (unsigned)i, (unsigned)(i + half)).a;
    else          bits = tf2x32(hk0, hk1, (unsigned)(i - half), (unsigned)i).b;
    float f = __uint_as_float((bits >> 9) | 0x3F800000u) - 1.0f;
    const float lo = -0x1.fffffep-1f;
    float u = fmaxf(lo, fmaf(f, 2.0f, lo));
    v = fmaf(0.225f, 1.41421356237f * erfinv_xla(u), 0.5f);
  } else {
    v = 0.0f;
  }
  s0[idx] = v;
}

// ---------------------------------------------------------------------------
// One NCA step (MFMA). LDS map (bytes):
//   [0      .. 24576)  P   [64 rows][384B]  perception f32, swizzled
//   [24576  .. 32768)  h1c [64 rows][128B]  layer1 chunk f32, swizzled
//                      (also: fire[64] f32 at 24576 in epilogue;
//                       also: sS halo f32[3132] at 24576 in phase 1/2)
//   [32768  .. 65536)  h2  [64 rows][512B]  layer2 out f32, swizzled
// ---------------------------------------------------------------------------
__global__ __launch_bounds__(256) void nca_step(
    const float* __restrict__ sin_, float* __restrict__ sout,
    const unsigned short* __restrict__ w1h, const unsigned short* __restrict__ w1l,
    const float* __restrict__ b1,
    const unsigned short* __restrict__ w2h, const unsigned short* __restrict__ w2l,
    const unsigned short* __restrict__ w3h, const unsigned short* __restrict__ w3l,
    float tval, unsigned fk0, unsigned fk1) {
  __shared__ __align__(16) char lds[65536];
  char* Pc = lds;                               // P rows 384B
  char* h1c = lds + 24576;                      // rows 128B
  char* h2c = lds + 32768;                      // rows 512B
  float* sS = (float*)(lds + 24576);            // [29][6][18] f32 (phase 1/2)
  float* fireLds = (float*)(lds + 24576);       // [64] (epilogue)

  const int tid = threadIdx.x;
  const int w = tid >> 6;        // wave id = m-strip
  const int L = tid & 63;
  const int lane16 = L & 15;
  const int quad = L >> 4;
  const int b = blockIdx.z;
  const int ty0 = blockIdx.y * 4;
  const int tx0 = blockIdx.x * 16;
  const float* sb = sin_ + b * 29 * 4096;

  // --- P1: halo load (29 ch x 6 rows x 18 cols, zero-padded) ---
  for (int l = tid; l < 29 * 108; l += 256) {
    int c = l / 108;
    int rem = l - c * 108;
    int r = rem / 18;
    int x = rem - r * 18;
    int gy = ty0 - 1 + r, gx = tx0 - 1 + x;
    float v = 0.0f;
    if ((unsigned)gy < 64u && (unsigned)gx < 64u) v = sb[c * 4096 + gy * 64 + gx];
    sS[l] = v;
  }
  __syncthreads();

  // --- P2: perception -> P (f32, swizzled rows of 96 slots) ---
  for (int sl = tid; sl < 64 * 96; sl += 256) {
    int m = sl & 63;
    int k = sl >> 6;
    int ly = m >> 4, lx = m & 15;
    float v;
    if (k < 29) {
      v = sS[k * 108 + (ly + 1) * 18 + (lx + 1)];
    } else if (k < 58) {
      const float* S = sS + (k - 29) * 108 + (ly + 1) * 18 + (lx + 1);
      v = ((S[-17] - S[-19]) + 2.0f * (S[1] - S[-1]) + (S[19] - S[17])) * 0.125f;
    } else if (k < 87) {
      const float* S = sS + (k - 58) * 108 + (ly + 1) * 18 + (lx + 1);
      v = ((S[17] + 2.0f * S[18] + S[19]) - (S[-19] + 2.0f * S[-18] + S[-17])) * 0.125f;
    } else if (k == 87) {
      v = tval;
    } else {
      v = 0.0f;
    }
    *(float*)(Pc + m * 384 + swz(m, k * 4)) = v;
  }
  __syncthreads();

  const int am = w * 16 + lane16;  // A-fragment row (this wave's strip)

  // --- A1 fragments (perception), resident: 3 kchunks x hi/lo ---
  bf16x8 a1h[3], a1l[3];
#pragma unroll
  for (int kc = 0; kc < 3; ++kc) {
    float4 f0 = *(const float4*)(Pc + am * 384 + swz(am, kc * 128 + quad * 32));
    float4 f1 = *(const float4*)(Pc + am * 384 + swz(am, kc * 128 + quad * 32 + 16));
    float v[8] = {f0.x, f0.y, f0.z, f0.w, f1.x, f1.y, f1.z, f1.w};
    split8(v, a1h[kc], a1l[kc]);
  }

  // --- fused layer1 -> layer2 over 8 n-chunks of 32 ---
  f32x4 acc2[8];
#pragma unroll
  for (int t = 0; t < 8; ++t) acc2[t] = (f32x4){0.f, 0.f, 0.f, 0.f};

#pragma unroll 1
  for (int nc = 0; nc < 8; ++nc) {
    // layer1 chunk: 2 C-tiles (cols nc*32 .. nc*32+31)
    f32x4 c0 = (f32x4){0.f, 0.f, 0.f, 0.f};
    f32x4 c1 = (f32x4){0.f, 0.f, 0.f, 0.f};
#pragma unroll
    for (int kc = 0; kc < 3; ++kc) {
      const int koff = kc * 32 + quad * 8;
      bf16x8 bh0 = *(const bf16x8*)(w1h + (nc * 32 + lane16) * 96 + koff);
      bf16x8 bl0 = *(const bf16x8*)(w1l + (nc * 32 + lane16) * 96 + koff);
      bf16x8 bh1 = *(const bf16x8*)(w1h + (nc * 32 + 16 + lane16) * 96 + koff);
      bf16x8 bl1 = *(const bf16x8*)(w1l + (nc * 32 + 16 + lane16) * 96 + koff);
      c0 = MFMA(a1h[kc], bh0, c0);
      c0 = MFMA(a1h[kc], bl0, c0);
      c0 = MFMA(a1l[kc], bh0, c0);
      c1 = MFMA(a1h[kc], bh1, c1);
      c1 = MFMA(a1h[kc], bl1, c1);
      c1 = MFMA(a1l[kc], bh1, c1);
    }
    // bias + leaky -> h1c (wave-private rows; no barrier needed)
    float bv0 = b1[nc * 32 + lane16];
    float bv1 = b1[nc * 32 + 16 + lane16];
#pragma unroll
    for (int r = 0; r < 4; ++r) {
      int m = w * 16 + quad * 4 + r;
      *(float*)(h1c + m * 128 + swz(m, lane16 * 4)) = leaky(c0[r] + bv0);
      *(float*)(h1c + m * 128 + swz(m, (16 + lane16) * 4)) = leaky(c1[r] + bv1);
    }
    // layer2 partial: A-frag from h1c (this chunk is k = nc*32..nc*32+31)
    float4 f0 = *(const float4*)(h1c + am * 128 + swz(am, quad * 32));
    float4 f1 = *(const float4*)(h1c + am * 128 + swz(am, quad * 32 + 16));
    float v[8] = {f0.x, f0.y, f0.z, f0.w, f1.x, f1.y, f1.z, f1.w};
    bf16x8 ah, al;
    split8(v, ah, al);
#pragma unroll
    for (int t = 0; t < 8; ++t) {
      const int koff = nc * 32 + quad * 8;
      bf16x8 bh = *(const bf16x8*)(w2h + (t * 16 + lane16) * 256 + koff);
      bf16x8 bl = *(const bf16x8*)(w2l + (t * 16 + lane16) * 256 + koff);
      acc2[t] = MFMA(ah, bh, acc2[t]);
      acc2[t] = MFMA(ah, bl, acc2[t]);
      acc2[t] = MFMA(al, bh, acc2[t]);
    }
  }

  // --- fire mask (wave 0 writes rows 0..1 of h1c region = its own rows) ---
  if (tid < 64) {
    int m = tid;
    int gy = ty0 + (m >> 4), gx = tx0 + (m & 15);
    int i = b * 4096 + gy * 64 + gx;
    unsigned bits;
    if (i < 32768) bits = tf2x32(fk0, fk1, (unsigned)i, (unsigned)(i + 32768)).a;
    else           bits = tf2x32(fk0, fk1, (unsigned)(i - 32768), (unsigned)i).b;
    fireLds[m] = (bits & 0x80000000u) ? 0.0f : 1.0f;
  }

  // --- h2 epilogue: leaky -> h2 LDS (wave-private rows) ---
#pragma unroll
  for (int t = 0; t < 8; ++t) {
#pragma unroll
    for (int r = 0; r < 4; ++r) {
      int m = w * 16 + quad * 4 + r;
      *(float*)(h2c + m * 512 + swz(m, (t * 16 + lane16) * 4)) = leaky(acc2[t][r]);
    }
  }
  __syncthreads();  // for fireLds (h2 rows are wave-private anyway)

  // --- layer3: 2 C-tiles (N=32), K=128 ---
  f32x4 d0 = (f32x4){0.f, 0.f, 0.f, 0.f};
  f32x4 d1 = (f32x4){0.f, 0.f, 0.f, 0.f};
#pragma unroll
  for (int kc = 0; kc < 4; ++kc) {
    float4 f0 = *(const float4*)(h2c + am * 512 + swz(am, kc * 128 + quad * 32));
    float4 f1 = *(const float4*)(h2c + am * 512 + swz(am, kc * 128 + quad * 32 + 16));
    float v[8] = {f0.x, f0.y, f0.z, f0.w, f1.x, f1.y, f1.z, f1.w};
    bf16x8 ah, al;
    split8(v, ah, al);
    const int koff = kc * 32 + quad * 8;
    bf16x8 bh0 = *(const bf16x8*)(w3h + lane16 * 128 + koff);
    bf16x8 bl0 = *(const bf16x8*)(w3l + lane16 * 128 + koff);
    bf16x8 bh1 = *(const bf16x8*)(w3h + (16 + lane16) * 128 + koff);
    bf16x8 bl1 = *(const bf16x8*)(w3l + (16 + lane16) * 128 + koff);
    d0 = MFMA(ah, bh0, d0);
    d0 = MFMA(ah, bl0, d0);
    d0 = MFMA(al, bh0, d0);
    d1 = MFMA(ah, bh1, d1);
    d1 = MFMA(ah, bl1, d1);
    d1 = MFMA(al, bh1, d1);
  }

  // --- epilogue: residual + fire, vectorized float4 per quad-row ---
  float4 fv = *(const float4*)(fireLds + w * 16 + quad * 4);
  const float fr[4] = {fv.x, fv.y, fv.z, fv.w};
  int gy = ty0 + w;
  int gxq = tx0 + quad * 4;
  float* ob = sout + b * 29 * 4096;
#pragma unroll
  for (int t3 = 0; t3 < 2; ++t3) {
    int c = t3 * 16 + lane16;
    if (c >= 3 && c <= 28) {
      float4 so = *(const float4*)(sb + c * 4096 + gy * 64 + gxq);
      f32x4 d = t3 ? d1 : d0;
      float4 o;
      o.x = fmaf(fr[0], d[0], so.x);
      o.y = fmaf(fr[1], d[1], so.y);
      o.z = fmaf(fr[2], d[2], so.z);
      o.w = fmaf(fr[3], d[3], so.w);
      *(float4*)(ob + c * 4096 + gy * 64 + gxq) = o;
    }
  }
}

// ---------------------------------------------------------------------------
__global__ __launch_bounds__(256) void finalize(const float* __restrict__ s,
                                                float* __restrict__ out) {
  __shared__ float red[256];
  __shared__ float ls[10];
  int b = blockIdx.x, tid = threadIdx.x;
  const float* sb = s + b * 29 * 4096;
  for (int o = 0; o < 10; ++o) {
    const float* ch = sb + (19 + o) * 4096;
    float p = 0.0f;
    for (int i = tid; i < 4096; i += 256) p += ch[i];
    red[tid] = p;
    __syncthreads();
    for (int st = 128; st > 0; st >>= 1) {
      if (tid < st) red[tid] += red[tid + st];
      __syncthreads();
    }
    if (tid == 0) ls[o] = red[0] * (1.0f / 4096.0f);
    __syncthreads();
  }
  if (tid == 0) {
    float m = ls[0];
    for (int o = 1; o < 10; ++o) m = fmaxf(m, ls[o]);
    float e[10], sum = 0.0f;
    for (int o = 0; o < 10; ++o) { e[o] = expf(ls[o] - m); sum += e[o]; }
    for (int o = 0; o < 10; ++o) out[b * 10 + o] = e[o] / sum;
  }
}

// ---------------------------------------------------------------------------
extern "C" void kernel_launch(void* const* d_in, const int* in_sizes, int n_in,
                              void* d_out, int out_size, void* d_ws, size_t ws_size,
                              hipStream_t stream) {
  const float* x  = (const float*)d_in[0];
  const float* w1 = (const float*)d_in[1];
  const float* b1 = (const float*)d_in[2];
  const float* w2 = (const float*)d_in[3];
  const float* w3 = (const float*)d_in[4];
  const int STEPS = 20;  // setup_inputs() fixes steps=20

  const size_t STATE = (size_t)16 * 29 * 4096;
  float* ws = (float*)d_ws;
  float* s0 = ws;
  float* s1 = ws + STATE;
  unsigned short* wb = (unsigned short*)(ws + 2 * STATE);
  unsigned short* w1h = wb;              // 256*96
  unsigned short* w1l = w1h + 24576;
  unsigned short* w2h = w1l + 24576;     // 128*256
  unsigned short* w2l = w2h + 32768;
  unsigned short* w3h = w2l + 32768;     // 32*128
  unsigned short* w3l = w3h + 4096;
  (void)ws_size; (void)n_in; (void)in_sizes; (void)out_size;

  prep_weights<<<128, 256, 0, stream>>>(w1, w2, w3, w1h, w1l, w2h, w2l, w3h, w3l);

  U2 hk = tf2x32(0u, 42u, 0u, 10000u);  // fold_in(key(42), 10000)
  init_state<<<(16 * 29 * 4096 + 255) / 256, 256, 0, stream>>>(x, s0, s1, hk.a, hk.b);

  for (int s = 0; s < STEPS; ++s) {
    U2 fk = tf2x32(0u, 42u, 0u, (unsigned)s);  // fold_in(key(42), step)
    float tval = (float)s / 100.0f;
    const float* in = (s & 1) ? s1 : s0;
    float* out = (s & 1) ? s0 : s1;
    dim3 grid(4, 16, 16);  // 16-wide x-tiles, 4-tall y-tiles, batch
    nca_step<<<grid, 256, 0, stream>>>(in, out, w1h, w1l, b1, w2h, w2l, w3h, w3l,
                                       tval, fk.a, fk.b);
  }
  finalize<<<16, 256, 0, stream>>>(s0, (float*)d_out);
}

// Round 4
// 1177.470 us; speedup vs baseline: 5.7137x; 1.8545x over previous
//
#include <hip/hip_runtime.h>

// ---------------------------------------------------------------------------
// ClassificationNCA — Round 3: R2 structure + fragment-major packed weights.
// Every MFMA B-tile's 64 lane-fragments (16 B each) are contiguous (1 KB/tile)
// -> B loads are fully coalesced global_load_dwordx4 at base + L*16, identical
// across waves (L1 hits), instead of 16-row stride-192B gathers.
// ---------------------------------------------------------------------------

#define ROTL32(x, d) (((x) << (d)) | ((x) >> (32 - (d))))

struct U2 { unsigned a, b; };

__host__ __device__ inline U2 tf2x32(unsigned k0, unsigned k1, unsigned c0, unsigned c1) {
  unsigned ks2 = k0 ^ k1 ^ 0x1BD11BDAu;
  unsigned x0 = c0 + k0;
  unsigned x1 = c1 + k1;
#define TF_ROUND4(r0, r1, r2, r3)                                              \
  x0 += x1; x1 = ROTL32(x1, r0); x1 ^= x0;                                     \
  x0 += x1; x1 = ROTL32(x1, r1); x1 ^= x0;                                     \
  x0 += x1; x1 = ROTL32(x1, r2); x1 ^= x0;                                     \
  x0 += x1; x1 = ROTL32(x1, r3); x1 ^= x0;
  TF_ROUND4(13, 15, 26, 6)
  x0 += k1;  x1 += ks2 + 1u;
  TF_ROUND4(17, 29, 16, 24)
  x0 += ks2; x1 += k0 + 2u;
  TF_ROUND4(13, 15, 26, 6)
  x0 += k0;  x1 += k1 + 3u;
  TF_ROUND4(17, 29, 16, 24)
  x0 += k1;  x1 += ks2 + 4u;
  TF_ROUND4(13, 15, 26, 6)
  x0 += ks2; x1 += k0 + 5u;
#undef TF_ROUND4
  U2 r; r.a = x0; r.b = x1; return r;
}

__device__ inline float erfinv_xla(float x) {
  float w = -log1pf(-x * x);
  float p;
  if (w < 5.0f) {
    w -= 2.5f;
    p = 2.81022636e-08f;
    p = fmaf(p, w, 3.43273939e-07f);
    p = fmaf(p, w, -3.5233877e-06f);
    p = fmaf(p, w, -4.39150654e-06f);
    p = fmaf(p, w, 0.00021858087f);
    p = fmaf(p, w, -0.00125372503f);
    p = fmaf(p, w, -0.00417768164f);
    p = fmaf(p, w, 0.246640727f);
    p = fmaf(p, w, 1.50140941f);
  } else {
    w = sqrtf(w) - 3.0f;
    p = -0.000200214257f;
    p = fmaf(p, w, 0.000100950558f);
    p = fmaf(p, w, 0.00134934322f);
    p = fmaf(p, w, -0.00367342844f);
    p = fmaf(p, w, 0.00573950773f);
    p = fmaf(p, w, -0.0076224613f);
    p = fmaf(p, w, 0.00943887047f);
    p = fmaf(p, w, 1.00167406f);
    p = fmaf(p, w, 2.83297682f);
  }
  return p * x;
}

__device__ inline float leaky(float v) { return v >= 0.0f ? v : 0.01f * v; }

typedef __attribute__((ext_vector_type(8))) short bf16x8;
typedef __attribute__((ext_vector_type(4))) float f32x4;

__host__ __device__ inline unsigned short bf16_rne(float x) {
  unsigned u = __float_as_uint(x);
  return (unsigned short)((u + 0x7FFFu + ((u >> 16) & 1u)) >> 16);
}

__device__ inline void split8(const float v[8], bf16x8& hi, bf16x8& lo) {
#pragma unroll
  for (int j = 0; j < 8; ++j) {
    unsigned short h = bf16_rne(v[j]);
    float hf = __uint_as_float(((unsigned)h) << 16);
    unsigned short l = bf16_rne(v[j] - hf);
    hi[j] = (short)h;
    lo[j] = (short)l;
  }
}

// XOR swizzle of 16B groups within 128B octets (LDS bank-conflict breaker).
__device__ inline int swz(int m, int byteoff) {
  int g = byteoff >> 4;
  g = (g & ~7) | ((g ^ (m & 7)) & 7);
  return (g << 4) | (byteoff & 15);
}

#define MFMA(a, b, c) __builtin_amdgcn_mfma_f32_16x16x32_bf16((a), (b), (c), 0, 0, 0)

// ---------------------------------------------------------------------------
// Weight prep: pack B-fragments fragment-major, 1 KB per MFMA B-tile.
// B-frag layout for 16x16x32: lane L holds B[k=k0+(L>>4)*8+j][n=n0+(L&15)],
// packed at tile_base + L*8 + j shorts.
//   pw1: tiles [nc(8)][kc(3)][f(4): (nt0,h),(nt0,l),(nt1,h),(nt1,l)]  96 KB
//   pw2: tiles [nc(8)][t(8)][h,l]                                    128 KB
//   pw3: tiles [kc(4)][f(4): (nt0,h),(nt0,l),(nt1,h),(nt1,l)]         16 KB
// ---------------------------------------------------------------------------
__global__ void prep_weights(const float* __restrict__ w1, const float* __restrict__ w2,
                             const float* __restrict__ w3,
                             unsigned short* __restrict__ pw1,
                             unsigned short* __restrict__ pw2,
                             unsigned short* __restrict__ pw3) {
  int i = blockIdx.x * 256 + threadIdx.x;
  int e = i & 511, L = e >> 3, j = e & 7;
  int kq = (L >> 4) * 8 + j;   // k within 32-chunk
  int ln = L & 15;             // n within 16-tile
  if (i < 96 * 512) {          // pw1
    int tile = i >> 9;
    int f = tile & 3, kc = (tile >> 2) % 3, nc = tile / 12;
    int n = nc * 32 + (f >> 1) * 16 + ln;
    int k = kc * 32 + kq;
    float v = (k < 88) ? w1[n * 88 + k] : 0.0f;
    unsigned short h = bf16_rne(v);
    pw1[i] = (f & 1) ? bf16_rne(v - __uint_as_float(((unsigned)h) << 16)) : h;
  }
  if (i < 128 * 512) {         // pw2
    int tile = i >> 9;
    int hl = tile & 1, t = (tile >> 1) & 7, nc = tile >> 4;
    int n = t * 16 + ln;
    int k = nc * 32 + kq;
    float v = w2[n * 256 + k];
    unsigned short h = bf16_rne(v);
    pw2[i] = hl ? bf16_rne(v - __uint_as_float(((unsigned)h) << 16)) : h;
  }
  if (i < 16 * 512) {          // pw3
    int tile = i >> 9;
    int f = tile & 3, kc = tile >> 2;
    int n = (f >> 1) * 16 + ln;
    int k = kc * 32 + kq;
    float v = (n < 29) ? w3[n * 128 + k] : 0.0f;
    unsigned short h = bf16_rne(v);
    pw3[i] = (f & 1) ? bf16_rne(v - __uint_as_float(((unsigned)h) << 16)) : h;
  }
}

// ---------------------------------------------------------------------------
// State init (channels 0..2 = x static in BOTH buffers).
// ---------------------------------------------------------------------------
__global__ void init_state(const float* __restrict__ x, float* __restrict__ s0,
                           float* __restrict__ s1, unsigned hk0, unsigned hk1) {
  int idx = blockIdx.x * 256 + threadIdx.x;
  if (idx >= 16 * 29 * 4096) return;
  int pix = idx & 4095;
  int c = (idx >> 12) % 29;
  int b = idx / (4096 * 29);
  float v;
  if (c < 3) {
    v = x[(b * 3 + c) * 4096 + pix];
    s1[idx] = v;
  } else if (c < 19) {
    int ch = c - 3;
    int i = (b * 16 + ch) * 4096 + pix;
    const int half = 131072;
    unsigned bits;
    if (i < half) bits = tf2x32(hk0, hk1, (unsigned)i, (unsigned)(i + half)).a;
    else          bits = tf2x32(hk0, hk1, (unsigned)(i - half), (unsigned)i).b;
    float f = __uint_as_float((bits >> 9) | 0x3F800000u) - 1.0f;
    const float lo = -0x1.fffffep-1f;
    float u = fmaxf(lo, fmaf(f, 2.0f, lo));
    v = fmaf(0.225f, 1.41421356237f * erfinv_xla(u), 0.5f);
  } else {
    v = 0.0f;
  }
  s0[idx] = v;
}

// ---------------------------------------------------------------------------
// One NCA step (MFMA). LDS map (bytes):
//   [0      .. 24576)  P   [64 rows][384B]  perception f32, swizzled
//   [24576  .. 32768)  h1c [64 rows][128B]  layer1 chunk f32, swizzled
//                      (also: sS halo f32[3132] / fire[64] — phase-reused)
//   [32768  .. 65536)  h2  [64 rows][512B]  layer2 out f32, swizzled
// ---------------------------------------------------------------------------
__global__ __launch_bounds__(256) void nca_step(
    const float* __restrict__ sin_, float* __restrict__ sout,
    const unsigned short* __restrict__ pw1, const float* __restrict__ b1,
    const unsigned short* __restrict__ pw2, const unsigned short* __restrict__ pw3,
    float tval, unsigned fk0, unsigned fk1) {
  __shared__ __align__(16) char lds[65536];
  char* Pc = lds;
  char* h1c = lds + 24576;
  char* h2c = lds + 32768;
  float* sS = (float*)(lds + 24576);
  float* fireLds = (float*)(lds + 24576);

  const int tid = threadIdx.x;
  const int w = tid >> 6;
  const int L = tid & 63;
  const int lane16 = L & 15;
  const int quad = L >> 4;
  const int b = blockIdx.z;
  const int ty0 = blockIdx.y * 4;
  const int tx0 = blockIdx.x * 16;
  const float* sb = sin_ + b * 29 * 4096;

  // --- P1: halo load (29 ch x 6 rows x 18 cols, zero-padded) ---
  for (int l = tid; l < 29 * 108; l += 256) {
    int c = l / 108;
    int rem = l - c * 108;
    int r = rem / 18;
    int x = rem - r * 18;
    int gy = ty0 - 1 + r, gx = tx0 - 1 + x;
    float v = 0.0f;
    if ((unsigned)gy < 64u && (unsigned)gx < 64u) v = sb[c * 4096 + gy * 64 + gx];
    sS[l] = v;
  }
  __syncthreads();

  // --- P2: perception -> P (f32, swizzled rows of 96 slots) ---
  for (int sl = tid; sl < 64 * 96; sl += 256) {
    int m = sl & 63;
    int k = sl >> 6;
    int ly = m >> 4, lx = m & 15;
    float v;
    if (k < 29) {
      v = sS[k * 108 + (ly + 1) * 18 + (lx + 1)];
    } else if (k < 58) {
      const float* S = sS + (k - 29) * 108 + (ly + 1) * 18 + (lx + 1);
      v = ((S[-17] - S[-19]) + 2.0f * (S[1] - S[-1]) + (S[19] - S[17])) * 0.125f;
    } else if (k < 87) {
      const float* S = sS + (k - 58) * 108 + (ly + 1) * 18 + (lx + 1);
      v = ((S[17] + 2.0f * S[18] + S[19]) - (S[-19] + 2.0f * S[-18] + S[-17])) * 0.125f;
    } else if (k == 87) {
      v = tval;
    } else {
      v = 0.0f;
    }
    *(float*)(Pc + m * 384 + swz(m, k * 4)) = v;
  }
  __syncthreads();

  const int am = w * 16 + lane16;
  const int L16 = L * 16;  // byte offset of this lane's packed fragment

  // --- A1 fragments (perception), resident: 3 kchunks x hi/lo ---
  bf16x8 a1h[3], a1l[3];
#pragma unroll
  for (int kc = 0; kc < 3; ++kc) {
    float4 f0 = *(const float4*)(Pc + am * 384 + swz(am, kc * 128 + quad * 32));
    float4 f1 = *(const float4*)(Pc + am * 384 + swz(am, kc * 128 + quad * 32 + 16));
    float v[8] = {f0.x, f0.y, f0.z, f0.w, f1.x, f1.y, f1.z, f1.w};
    split8(v, a1h[kc], a1l[kc]);
  }

  // --- fused layer1 -> layer2 over 8 n-chunks of 32 ---
  f32x4 acc2[8];
#pragma unroll
  for (int t = 0; t < 8; ++t) acc2[t] = (f32x4){0.f, 0.f, 0.f, 0.f};

#pragma unroll 1
  for (int nc = 0; nc < 8; ++nc) {
    f32x4 c0 = (f32x4){0.f, 0.f, 0.f, 0.f};
    f32x4 c1 = (f32x4){0.f, 0.f, 0.f, 0.f};
#pragma unroll
    for (int kc = 0; kc < 3; ++kc) {
      const char* g = (const char*)pw1 + (nc * 3 + kc) * 4096;  // 4 tiles of 1 KB
      bf16x8 bh0 = *(const bf16x8*)(g + L16);
      bf16x8 bl0 = *(const bf16x8*)(g + 1024 + L16);
      bf16x8 bh1 = *(const bf16x8*)(g + 2048 + L16);
      bf16x8 bl1 = *(const bf16x8*)(g + 3072 + L16);
      c0 = MFMA(a1h[kc], bh0, c0);
      c0 = MFMA(a1h[kc], bl0, c0);
      c0 = MFMA(a1l[kc], bh0, c0);
      c1 = MFMA(a1h[kc], bh1, c1);
      c1 = MFMA(a1h[kc], bl1, c1);
      c1 = MFMA(a1l[kc], bh1, c1);
    }
    float bv0 = b1[nc * 32 + lane16];
    float bv1 = b1[nc * 32 + 16 + lane16];
#pragma unroll
    for (int r = 0; r < 4; ++r) {
      int m = w * 16 + quad * 4 + r;
      *(float*)(h1c + m * 128 + swz(m, lane16 * 4)) = leaky(c0[r] + bv0);
      *(float*)(h1c + m * 128 + swz(m, (16 + lane16) * 4)) = leaky(c1[r] + bv1);
    }
    float4 f0 = *(const float4*)(h1c + am * 128 + swz(am, quad * 32));
    float4 f1 = *(const float4*)(h1c + am * 128 + swz(am, quad * 32 + 16));
    float v[8] = {f0.x, f0.y, f0.z, f0.w, f1.x, f1.y, f1.z, f1.w};
    bf16x8 ah, al;
    split8(v, ah, al);
#pragma unroll
    for (int t = 0; t < 8; ++t) {
      const char* g = (const char*)pw2 + (nc * 8 + t) * 2048;  // h tile + l tile
      bf16x8 bh = *(const bf16x8*)(g + L16);
      bf16x8 bl = *(const bf16x8*)(g + 1024 + L16);
      acc2[t] = MFMA(ah, bh, acc2[t]);
      acc2[t] = MFMA(ah, bl, acc2[t]);
      acc2[t] = MFMA(al, bh, acc2[t]);
    }
  }

  // --- fire mask ---
  if (tid < 64) {
    int m = tid;
    int gy = ty0 + (m >> 4), gx = tx0 + (m & 15);
    int i = b * 4096 + gy * 64 + gx;
    unsigned bits;
    if (i < 32768) bits = tf2x32(fk0, fk1, (unsigned)i, (unsigned)(i + 32768)).a;
    else           bits = tf2x32(fk0, fk1, (unsigned)(i - 32768), (unsigned)i).b;
    fireLds[m] = (bits & 0x80000000u) ? 0.0f : 1.0f;
  }

  // --- h2 epilogue: leaky -> h2 LDS (wave-private rows) ---
#pragma unroll
  for (int t = 0; t < 8; ++t) {
#pragma unroll
    for (int r = 0; r < 4; ++r) {
      int m = w * 16 + quad * 4 + r;
      *(float*)(h2c + m * 512 + swz(m, (t * 16 + lane16) * 4)) = leaky(acc2[t][r]);
    }
  }
  __syncthreads();  // for fireLds

  // --- layer3: 2 C-tiles (N=32), K=128 ---
  f32x4 d0 = (f32x4){0.f, 0.f, 0.f, 0.f};
  f32x4 d1 = (f32x4){0.f, 0.f, 0.f, 0.f};
#pragma unroll
  for (int kc = 0; kc < 4; ++kc) {
    float4 f0 = *(const float4*)(h2c + am * 512 + swz(am, kc * 128 + quad * 32));
    float4 f1 = *(const float4*)(h2c + am * 512 + swz(am, kc * 128 + quad * 32 + 16));
    float v[8] = {f0.x, f0.y, f0.z, f0.w, f1.x, f1.y, f1.z, f1.w};
    bf16x8 ah, al;
    split8(v, ah, al);
    const char* g = (const char*)pw3 + kc * 4096;
    bf16x8 bh0 = *(const bf16x8*)(g + L16);
    bf16x8 bl0 = *(const bf16x8*)(g + 1024 + L16);
    bf16x8 bh1 = *(const bf16x8*)(g + 2048 + L16);
    bf16x8 bl1 = *(const bf16x8*)(g + 3072 + L16);
    d0 = MFMA(ah, bh0, d0);
    d0 = MFMA(ah, bl0, d0);
    d0 = MFMA(al, bh0, d0);
    d1 = MFMA(ah, bh1, d1);
    d1 = MFMA(ah, bl1, d1);
    d1 = MFMA(al, bh1, d1);
  }

  // --- epilogue: residual + fire, vectorized float4 per quad-row ---
  float4 fv = *(const float4*)(fireLds + w * 16 + quad * 4);
  const float fr[4] = {fv.x, fv.y, fv.z, fv.w};
  int gy = ty0 + w;
  int gxq = tx0 + quad * 4;
  float* ob = sout + b * 29 * 4096;
#pragma unroll
  for (int t3 = 0; t3 < 2; ++t3) {
    int c = t3 * 16 + lane16;
    if (c >= 3 && c <= 28) {
      float4 so = *(const float4*)(sb + c * 4096 + gy * 64 + gxq);
      f32x4 d = t3 ? d1 : d0;
      float4 o;
      o.x = fmaf(fr[0], d[0], so.x);
      o.y = fmaf(fr[1], d[1], so.y);
      o.z = fmaf(fr[2], d[2], so.z);
      o.w = fmaf(fr[3], d[3], so.w);
      *(float4*)(ob + c * 4096 + gy * 64 + gxq) = o;
    }
  }
}

// ---------------------------------------------------------------------------
__global__ __launch_bounds__(256) void finalize(const float* __restrict__ s,
                                                float* __restrict__ out) {
  __shared__ float red[256];
  __shared__ float ls[10];
  int b = blockIdx.x, tid = threadIdx.x;
  const float* sb = s + b * 29 * 4096;
  for (int o = 0; o < 10; ++o) {
    const float* ch = sb + (19 + o) * 4096;
    float p = 0.0f;
    for (int i = tid; i < 4096; i += 256) p += ch[i];
    red[tid] = p;
    __syncthreads();
    for (int st = 128; st > 0; st >>= 1) {
      if (tid < st) red[tid] += red[tid + st];
      __syncthreads();
    }
    if (tid == 0) ls[o] = red[0] * (1.0f / 4096.0f);
    __syncthreads();
  }
  if (tid == 0) {
    float m = ls[0];
    for (int o = 1; o < 10; ++o) m = fmaxf(m, ls[o]);
    float e[10], sum = 0.0f;
    for (int o = 0; o < 10; ++o) { e[o] = expf(ls[o] - m); sum += e[o]; }
    for (int o = 0; o < 10; ++o) out[b * 10 + o] = e[o] / sum;
  }
}

// ---------------------------------------------------------------------------
extern "C" void kernel_launch(void* const* d_in, const int* in_sizes, int n_in,
                              void* d_out, int out_size, void* d_ws, size_t ws_size,
                              hipStream_t stream) {
  const float* x  = (const float*)d_in[0];
  const float* w1 = (const float*)d_in[1];
  const float* b1 = (const float*)d_in[2];
  const float* w2 = (const float*)d_in[3];
  const float* w3 = (const float*)d_in[4];
  const int STEPS = 20;  // setup_inputs() fixes steps=20

  const size_t STATE = (size_t)16 * 29 * 4096;
  float* ws = (float*)d_ws;
  float* s0 = ws;
  float* s1 = ws + STATE;
  unsigned short* pw1 = (unsigned short*)(ws + 2 * STATE);  // 96*512 shorts
  unsigned short* pw2 = pw1 + 96 * 512;                      // 128*512
  unsigned short* pw3 = pw2 + 128 * 512;                     // 16*512
  (void)ws_size; (void)n_in; (void)in_sizes; (void)out_size;

  prep_weights<<<256, 256, 0, stream>>>(w1, w2, w3, pw1, pw2, pw3);

  U2 hk = tf2x32(0u, 42u, 0u, 10000u);  // fold_in(key(42), 10000)
  init_state<<<(16 * 29 * 4096 + 255) / 256, 256, 0, stream>>>(x, s0, s1, hk.a, hk.b);

  for (int s = 0; s < STEPS; ++s) {
    U2 fk = tf2x32(0u, 42u, 0u, (unsigned)s);  // fold_in(key(42), step)
    float tval = (float)s / 100.0f;
    const float* in = (s & 1) ? s1 : s0;
    float* out = (s & 1) ? s0 : s1;
    dim3 grid(4, 16, 16);
    nca_step<<<grid, 256, 0, stream>>>(in, out, pw1, b1, pw2, pw3, tval, fk.a, fk.b);
  }
  finalize<<<16, 256, 0, stream>>>(s0, (float*)d_out);
}

// Round 5
// 987.511 us; speedup vs baseline: 6.8128x; 1.1924x over previous
//
#include <hip/hip_runtime.h>

// ---------------------------------------------------------------------------
// ClassificationNCA — Round 4: perception computed directly into A-fragments
// (K-permuted: [ps|pad][px|t|pad][py|pad], pw1 packed to match); h1/h2 stored
// as pre-split bf16 hi/lo LDS planes; fire mask via __shfl. LDS = 40960 B
// exactly -> 4 blocks/CU; 2 barriers/step; grid = 256 CU x 4 blocks.
// ---------------------------------------------------------------------------

#define ROTL32(x, d) (((x) << (d)) | ((x) >> (32 - (d))))

struct U2 { unsigned a, b; };

__host__ __device__ inline U2 tf2x32(unsigned k0, unsigned k1, unsigned c0, unsigned c1) {
  unsigned ks2 = k0 ^ k1 ^ 0x1BD11BDAu;
  unsigned x0 = c0 + k0;
  unsigned x1 = c1 + k1;
#define TF_ROUND4(r0, r1, r2, r3)                                              \
  x0 += x1; x1 = ROTL32(x1, r0); x1 ^= x0;                                     \
  x0 += x1; x1 = ROTL32(x1, r1); x1 ^= x0;                                     \
  x0 += x1; x1 = ROTL32(x1, r2); x1 ^= x0;                                     \
  x0 += x1; x1 = ROTL32(x1, r3); x1 ^= x0;
  TF_ROUND4(13, 15, 26, 6)
  x0 += k1;  x1 += ks2 + 1u;
  TF_ROUND4(17, 29, 16, 24)
  x0 += ks2; x1 += k0 + 2u;
  TF_ROUND4(13, 15, 26, 6)
  x0 += k0;  x1 += k1 + 3u;
  TF_ROUND4(17, 29, 16, 24)
  x0 += k1;  x1 += ks2 + 4u;
  TF_ROUND4(13, 15, 26, 6)
  x0 += ks2; x1 += k0 + 5u;
#undef TF_ROUND4
  U2 r; r.a = x0; r.b = x1; return r;
}

__device__ inline float erfinv_xla(float x) {
  float w = -log1pf(-x * x);
  float p;
  if (w < 5.0f) {
    w -= 2.5f;
    p = 2.81022636e-08f;
    p = fmaf(p, w, 3.43273939e-07f);
    p = fmaf(p, w, -3.5233877e-06f);
    p = fmaf(p, w, -4.39150654e-06f);
    p = fmaf(p, w, 0.00021858087f);
    p = fmaf(p, w, -0.00125372503f);
    p = fmaf(p, w, -0.00417768164f);
    p = fmaf(p, w, 0.246640727f);
    p = fmaf(p, w, 1.50140941f);
  } else {
    w = sqrtf(w) - 3.0f;
    p = -0.000200214257f;
    p = fmaf(p, w, 0.000100950558f);
    p = fmaf(p, w, 0.00134934322f);
    p = fmaf(p, w, -0.00367342844f);
    p = fmaf(p, w, 0.00573950773f);
    p = fmaf(p, w, -0.0076224613f);
    p = fmaf(p, w, 0.00943887047f);
    p = fmaf(p, w, 1.00167406f);
    p = fmaf(p, w, 2.83297682f);
  }
  return p * x;
}

__device__ inline float leaky(float v) { return v >= 0.0f ? v : 0.01f * v; }

typedef __attribute__((ext_vector_type(8))) short bf16x8;
typedef __attribute__((ext_vector_type(4))) float f32x4;

__host__ __device__ inline unsigned short bf16_rne(float x) {
  unsigned u = __float_as_uint(x);
  return (unsigned short)((u + 0x7FFFu + ((u >> 16) & 1u)) >> 16);
}

__device__ inline void split8(const float v[8], bf16x8& hi, bf16x8& lo) {
#pragma unroll
  for (int j = 0; j < 8; ++j) {
    unsigned short h = bf16_rne(v[j]);
    float hf = __uint_as_float(((unsigned)h) << 16);
    unsigned short l = bf16_rne(v[j] - hf);
    hi[j] = (short)h;
    lo[j] = (short)l;
  }
}

// XOR swizzles: 16B groups; 4-group window (64B rows) / 8-group window (256B).
__device__ inline int swz64(int m, int off) {
  int g = (off >> 4) ^ (m & 3);
  return (g << 4) | (off & 15);
}
__device__ inline int swz256(int m, int off) {
  int g = off >> 4;
  g = (g & ~7) | ((g ^ (m & 7)) & 7);
  return (g << 4) | (off & 15);
}

#define MFMA(a, b, c) __builtin_amdgcn_mfma_f32_16x16x32_bf16((a), (b), (c), 0, 0, 0)

// ---------------------------------------------------------------------------
// Weight prep: fragment-major packed B-tiles (1 KB/tile), as in R3.
// pw1 K-dim is PERMUTED to match direct perception fragments:
//   k-chunk kc=0: slot kq -> ps[kq]   (W1 col kq)    for kq<29 else 0
//   k-chunk kc=1: slot kq -> px[kq]   (col 29+kq) ; kq==29 -> t (col 87)
//   k-chunk kc=2: slot kq -> py[kq]   (col 58+kq)   for kq<29 else 0
// ---------------------------------------------------------------------------
__global__ void prep_weights(const float* __restrict__ w1, const float* __restrict__ w2,
                             const float* __restrict__ w3,
                             unsigned short* __restrict__ pw1,
                             unsigned short* __restrict__ pw2,
                             unsigned short* __restrict__ pw3) {
  int i = blockIdx.x * 256 + threadIdx.x;
  int e = i & 511, L = e >> 3, j = e & 7;
  int kq = (L >> 4) * 8 + j;   // k within 32-chunk
  int ln = L & 15;             // n within 16-tile
  if (i < 96 * 512) {          // pw1: [nc(8)][kc(3)][f(4)]
    int tile = i >> 9;
    int f = tile & 3, kc = (tile >> 2) % 3, nc = tile / 12;
    int n = nc * 32 + (f >> 1) * 16 + ln;
    int src;
    if (kc == 0)      src = (kq < 29) ? kq : -1;
    else if (kc == 1) src = (kq < 29) ? 29 + kq : ((kq == 29) ? 87 : -1);
    else              src = (kq < 29) ? 58 + kq : -1;
    float v = (src >= 0) ? w1[n * 88 + src] : 0.0f;
    unsigned short h = bf16_rne(v);
    pw1[i] = (f & 1) ? bf16_rne(v - __uint_as_float(((unsigned)h) << 16)) : h;
  }
  if (i < 128 * 512) {         // pw2: [nc(8)][t(8)][h,l]
    int tile = i >> 9;
    int hl = tile & 1, t = (tile >> 1) & 7, nc = tile >> 4;
    int n = t * 16 + ln;
    int k = nc * 32 + kq;
    float v = w2[n * 256 + k];
    unsigned short h = bf16_rne(v);
    pw2[i] = hl ? bf16_rne(v - __uint_as_float(((unsigned)h) << 16)) : h;
  }
  if (i < 16 * 512) {          // pw3: [kc(4)][f(4)]
    int tile = i >> 9;
    int f = tile & 3, kc = tile >> 2;
    int n = (f >> 1) * 16 + ln;
    int k = kc * 32 + kq;
    float v = (n < 29) ? w3[n * 128 + k] : 0.0f;
    unsigned short h = bf16_rne(v);
    pw3[i] = (f & 1) ? bf16_rne(v - __uint_as_float(((unsigned)h) << 16)) : h;
  }
}

// ---------------------------------------------------------------------------
__global__ void init_state(const float* __restrict__ x, float* __restrict__ s0,
                           float* __restrict__ s1, unsigned hk0, unsigned hk1) {
  int idx = blockIdx.x * 256 + threadIdx.x;
  if (idx >= 16 * 29 * 4096) return;
  int pix = idx & 4095;
  int c = (idx >> 12) % 29;
  int b = idx / (4096 * 29);
  float v;
  if (c < 3) {
    v = x[(b * 3 + c) * 4096 + pix];
    s1[idx] = v;
  } else if (c < 19) {
    int ch = c - 3;
    int i = (b * 16 + ch) * 4096 + pix;
    const int half = 131072;
    unsigned bits;
    if (i < half) bits = tf2x32(hk0, hk1, (unsigned)i, (unsigned)(i + half)).a;
    else          bits = tf2x32(hk0, hk1, (unsigned)(i - half), (unsigned)i).b;
    float f = __uint_as_float((bits >> 9) | 0x3F800000u) - 1.0f;
    const float lo = -0x1.fffffep-1f;
    float u = fmaxf(lo, fmaf(f, 2.0f, lo));
    v = fmaf(0.225f, 1.41421356237f * erfinv_xla(u), 0.5f);
  } else {
    v = 0.0f;
  }
  s0[idx] = v;
}

// ---------------------------------------------------------------------------
// One NCA step. LDS map (bytes), total 40960:
//   [0     ..  4096)  h1h  ushort[64][32], row 64 B, swz64
//   [4096  ..  8192)  h1l  ushort[64][32]
//   [8192  .. 24576)  h2h  ushort[64][128], row 256 B, swz256
//   [24576 .. 40960)  h2l  ushort[64][128]
//   sS halo float[29][6*18+1 stride 109] overlays [8192, 20836) (dead
//   before any h2 write; barrier 2 separates).
// ---------------------------------------------------------------------------
__global__ __launch_bounds__(256, 4) void nca_step(
    const float* __restrict__ sin_, float* __restrict__ sout,
    const unsigned short* __restrict__ pw1, const float* __restrict__ b1,
    const unsigned short* __restrict__ pw2, const unsigned short* __restrict__ pw3,
    float tval, unsigned fk0, unsigned fk1) {
  __shared__ __align__(16) char lds[40960];
  char* h1h = lds;
  char* h1l = lds + 4096;
  char* h2h = lds + 8192;
  char* h2l = lds + 24576;
  float* sS = (float*)(lds + 8192);   // channel stride 109 floats (bank-spread)

  const int tid = threadIdx.x;
  const int w = tid >> 6;
  const int L = tid & 63;
  const int lane16 = L & 15;
  const int quad = L >> 4;
  const int b = blockIdx.z;
  const int ty0 = blockIdx.y * 4;
  const int tx0 = blockIdx.x * 16;
  const float* sb = sin_ + b * 29 * 4096;

  // --- P1: halo load (29 ch x 6 rows x 18 cols, zero-padded) ---
  for (int l = tid; l < 29 * 108; l += 256) {
    int c = l / 108;
    int rem = l - c * 108;
    int r = rem / 18;
    int x = rem - r * 18;
    int gy = ty0 - 1 + r, gx = tx0 - 1 + x;
    float v = 0.0f;
    if ((unsigned)gy < 64u && (unsigned)gx < 64u) v = sb[c * 4096 + gy * 64 + gx];
    sS[c * 109 + r * 18 + x] = v;
  }
  __syncthreads();

  // --- A1 fragments directly from halo (permuted K: ps | px,t | py) ---
  // A row am = w*16+lane16 -> cell (ly=w, lx=lane16); lane channel c=quad*8+j.
  const int am = w * 16 + lane16;
  bf16x8 a1h[3], a1l[3];
  {
    float vps[8], vpx[8], vpy[8];
#pragma unroll
    for (int j = 0; j < 8; ++j) {
      int c = quad * 8 + j;
      int cc = (c < 29) ? c : 0;
      const float* S = sS + cc * 109 + (w + 1) * 18 + (lane16 + 1);
      float m00 = S[-19], m01 = S[-18], m02 = S[-17];
      float m10 = S[-1],  m11 = S[0],   m12 = S[1];
      float m20 = S[17],  m21 = S[18],  m22 = S[19];
      bool valid = (c < 29);
      vps[j] = valid ? m11 : 0.0f;
      float px = ((m02 - m00) + 2.0f * (m12 - m10) + (m22 - m20)) * 0.125f;
      float py = ((m20 + 2.0f * m21 + m22) - (m00 + 2.0f * m01 + m02)) * 0.125f;
      vpx[j] = valid ? px : ((c == 29) ? tval : 0.0f);
      vpy[j] = valid ? py : 0.0f;
    }
    split8(vps, a1h[0], a1l[0]);
    split8(vpx, a1h[1], a1l[1]);
    split8(vpy, a1h[2], a1l[2]);
  }
  __syncthreads();  // sS dead -> h2 region reusable

  const int L16 = L * 16;

  // --- fused layer1 -> layer2 over 8 n-chunks of 32 ---
  f32x4 acc2[8];
#pragma unroll
  for (int t = 0; t < 8; ++t) acc2[t] = (f32x4){0.f, 0.f, 0.f, 0.f};

#pragma unroll 1
  for (int nc = 0; nc < 8; ++nc) {
    f32x4 c0 = (f32x4){0.f, 0.f, 0.f, 0.f};
    f32x4 c1 = (f32x4){0.f, 0.f, 0.f, 0.f};
#pragma unroll
    for (int kc = 0; kc < 3; ++kc) {
      const char* g = (const char*)pw1 + (nc * 3 + kc) * 4096;
      bf16x8 bh0 = *(const bf16x8*)(g + L16);
      bf16x8 bl0 = *(const bf16x8*)(g + 1024 + L16);
      bf16x8 bh1 = *(const bf16x8*)(g + 2048 + L16);
      bf16x8 bl1 = *(const bf16x8*)(g + 3072 + L16);
      c0 = MFMA(a1h[kc], bh0, c0);
      c0 = MFMA(a1h[kc], bl0, c0);
      c0 = MFMA(a1l[kc], bh0, c0);
      c1 = MFMA(a1h[kc], bh1, c1);
      c1 = MFMA(a1h[kc], bl1, c1);
      c1 = MFMA(a1l[kc], bh1, c1);
    }
    // bias + leaky + SPLIT -> h1 hi/lo planes (wave-private rows)
    float bv0 = b1[nc * 32 + lane16];
    float bv1 = b1[nc * 32 + 16 + lane16];
#pragma unroll
    for (int r = 0; r < 4; ++r) {
      int m = w * 16 + quad * 4 + r;
      float v0 = leaky(c0[r] + bv0);
      float v1 = leaky(c1[r] + bv1);
      unsigned short h0 = bf16_rne(v0);
      unsigned short l0 = bf16_rne(v0 - __uint_as_float(((unsigned)h0) << 16));
      unsigned short h1v = bf16_rne(v1);
      unsigned short l1 = bf16_rne(v1 - __uint_as_float(((unsigned)h1v) << 16));
      *(unsigned short*)(h1h + m * 64 + swz64(m, lane16 * 2)) = h0;
      *(unsigned short*)(h1l + m * 64 + swz64(m, lane16 * 2)) = l0;
      *(unsigned short*)(h1h + m * 64 + swz64(m, 32 + lane16 * 2)) = h1v;
      *(unsigned short*)(h1l + m * 64 + swz64(m, 32 + lane16 * 2)) = l1;
    }
    // layer2 A-frags: direct bf16x8 reads (same wave's rows; lgkm-ordered)
    bf16x8 ah = *(const bf16x8*)(h1h + am * 64 + swz64(am, quad * 16));
    bf16x8 al = *(const bf16x8*)(h1l + am * 64 + swz64(am, quad * 16));
#pragma unroll
    for (int t = 0; t < 8; ++t) {
      const char* g = (const char*)pw2 + (nc * 8 + t) * 2048;
      bf16x8 bh = *(const bf16x8*)(g + L16);
      bf16x8 bl = *(const bf16x8*)(g + 1024 + L16);
      acc2[t] = MFMA(ah, bh, acc2[t]);
      acc2[t] = MFMA(ah, bl, acc2[t]);
      acc2[t] = MFMA(al, bh, acc2[t]);
    }
  }

  // --- h2 epilogue: leaky + split -> h2 hi/lo planes (wave-private rows) ---
#pragma unroll
  for (int t = 0; t < 8; ++t) {
#pragma unroll
    for (int r = 0; r < 4; ++r) {
      int m = w * 16 + quad * 4 + r;
      float v = leaky(acc2[t][r]);
      unsigned short h = bf16_rne(v);
      unsigned short l = bf16_rne(v - __uint_as_float(((unsigned)h) << 16));
      int off = (t * 16 + lane16) * 2;
      *(unsigned short*)(h2h + m * 256 + swz256(m, off)) = h;
      *(unsigned short*)(h2l + m * 256 + swz256(m, off)) = l;
    }
  }

  // --- fire mask in registers (lane computes cell m = w*16+lane16) ---
  float fire;
  {
    int i = b * 4096 + (ty0 + w) * 64 + (tx0 + lane16);
    unsigned bits;
    if (i < 32768) bits = tf2x32(fk0, fk1, (unsigned)i, (unsigned)(i + 32768)).a;
    else           bits = tf2x32(fk0, fk1, (unsigned)(i - 32768), (unsigned)i).b;
    fire = (bits & 0x80000000u) ? 0.0f : 1.0f;
  }

  // --- layer3: 2 C-tiles (N=32), K=128; A-frags direct from h2 planes ---
  f32x4 d0 = (f32x4){0.f, 0.f, 0.f, 0.f};
  f32x4 d1 = (f32x4){0.f, 0.f, 0.f, 0.f};
#pragma unroll
  for (int kc = 0; kc < 4; ++kc) {
    bf16x8 ah = *(const bf16x8*)(h2h + am * 256 + swz256(am, kc * 64 + quad * 16));
    bf16x8 al = *(const bf16x8*)(h2l + am * 256 + swz256(am, kc * 64 + quad * 16));
    const char* g = (const char*)pw3 + kc * 4096;
    bf16x8 bh0 = *(const bf16x8*)(g + L16);
    bf16x8 bl0 = *(const bf16x8*)(g + 1024 + L16);
    bf16x8 bh1 = *(const bf16x8*)(g + 2048 + L16);
    bf16x8 bl1 = *(const bf16x8*)(g + 3072 + L16);
    d0 = MFMA(ah, bh0, d0);
    d0 = MFMA(ah, bl0, d0);
    d0 = MFMA(al, bh0, d0);
    d1 = MFMA(ah, bh1, d1);
    d1 = MFMA(ah, bl1, d1);
    d1 = MFMA(al, bh1, d1);
  }

  // --- epilogue: residual + fire (fire values pulled via shuffle) ---
  float fr[4];
#pragma unroll
  for (int r = 0; r < 4; ++r) fr[r] = __shfl(fire, quad * 4 + r, 64);
  int gy = ty0 + w;
  int gxq = tx0 + quad * 4;
  float* ob = sout + b * 29 * 4096;
#pragma unroll
  for (int t3 = 0; t3 < 2; ++t3) {
    int c = t3 * 16 + lane16;
    if (c >= 3 && c <= 28) {
      float4 so = *(const float4*)(sb + c * 4096 + gy * 64 + gxq);
      f32x4 d = t3 ? d1 : d0;
      float4 o;
      o.x = fmaf(fr[0], d[0], so.x);
      o.y = fmaf(fr[1], d[1], so.y);
      o.z = fmaf(fr[2], d[2], so.z);
      o.w = fmaf(fr[3], d[3], so.w);
      *(float4*)(ob + c * 4096 + gy * 64 + gxq) = o;
    }
  }
}

// ---------------------------------------------------------------------------
__global__ __launch_bounds__(256) void finalize(const float* __restrict__ s,
                                                float* __restrict__ out) {
  __shared__ float red[256];
  __shared__ float ls[10];
  int b = blockIdx.x, tid = threadIdx.x;
  const float* sb = s + b * 29 * 4096;
  for (int o = 0; o < 10; ++o) {
    const float* ch = sb + (19 + o) * 4096;
    float p = 0.0f;
    for (int i = tid; i < 4096; i += 256) p += ch[i];
    red[tid] = p;
    __syncthreads();
    for (int st = 128; st > 0; st >>= 1) {
      if (tid < st) red[tid] += red[tid + st];
      __syncthreads();
    }
    if (tid == 0) ls[o] = red[0] * (1.0f / 4096.0f);
    __syncthreads();
  }
  if (tid == 0) {
    float m = ls[0];
    for (int o = 1; o < 10; ++o) m = fmaxf(m, ls[o]);
    float e[10], sum = 0.0f;
    for (int o = 0; o < 10; ++o) { e[o] = expf(ls[o] - m); sum += e[o]; }
    for (int o = 0; o < 10; ++o) out[b * 10 + o] = e[o] / sum;
  }
}

// ---------------------------------------------------------------------------
extern "C" void kernel_launch(void* const* d_in, const int* in_sizes, int n_in,
                              void* d_out, int out_size, void* d_ws, size_t ws_size,
                              hipStream_t stream) {
  const float* x  = (const float*)d_in[0];
  const float* w1 = (const float*)d_in[1];
  const float* b1 = (const float*)d_in[2];
  const float* w2 = (const float*)d_in[3];
  const float* w3 = (const float*)d_in[4];
  const int STEPS = 20;  // setup_inputs() fixes steps=20

  const size_t STATE = (size_t)16 * 29 * 4096;
  float* ws = (float*)d_ws;
  float* s0 = ws;
  float* s1 = ws + STATE;
  unsigned short* pw1 = (unsigned short*)(ws + 2 * STATE);  // 96*512 shorts
  unsigned short* pw2 = pw1 + 96 * 512;                      // 128*512
  unsigned short* pw3 = pw2 + 128 * 512;                     // 16*512
  (void)ws_size; (void)n_in; (void)in_sizes; (void)out_size;

  prep_weights<<<256, 256, 0, stream>>>(w1, w2, w3, pw1, pw2, pw3);

  U2 hk = tf2x32(0u, 42u, 0u, 10000u);  // fold_in(key(42), 10000)
  init_state<<<(16 * 29 * 4096 + 255) / 256, 256, 0, stream>>>(x, s0, s1, hk.a, hk.b);

  for (int s = 0; s < STEPS; ++s) {
    U2 fk = tf2x32(0u, 42u, 0u, (unsigned)s);  // fold_in(key(42), step)
    float tval = (float)s / 100.0f;
    const float* in = (s & 1) ? s1 : s0;
    float* out = (s & 1) ? s0 : s1;
    dim3 grid(4, 16, 16);
    nca_step<<<grid, 256, 0, stream>>>(in, out, pw1, b1, pw2, pw3, tval, fk.a, fk.b);
  }
  finalize<<<16, 256, 0, stream>>>(s0, (float*)d_out);
}